// Round 2
// baseline (259.341 us; speedup 1.0000x reference)
//
#include <hip/hip_runtime.h>

// FC_CPPN: per-pixel tiny MLP, ALL float32 (inputs, weights, output).
//  d_in[0]=x[N], [1]=y[N], [2]=r[N], [3]=z[N,8], [4]=W0[8,11], [5]=b0[8],
//  [6]=Wm[8,8], [7]=bm[8], [8]=Wo[3,8], [9]=bo[3], [10]=masks[3,4,2] (int)
// out: float32 [N,3]
//
// ws float layout: [0,88) W0 (cols 0..7 pre-scaled by 1/Z_SCALE), [88,96) b0,
// [96,160) Wm, [160,168) bm, [168,192) Wo, [192,195) bo.
// ws int layout:  ints [256,280) funid[l*8 + natural_column] = activation 0..3

__global__ void cppn_prep(const float* __restrict__ W0,
                          const float* __restrict__ b0,
                          const float* __restrict__ Wm,
                          const float* __restrict__ bm,
                          const float* __restrict__ Wo,
                          const float* __restrict__ bo,
                          const int* __restrict__ masks,
                          float* __restrict__ wf,
                          int* __restrict__ wi) {
    int t = threadIdx.x;
    if (t < 88) {
        int k = t % 11;
        // fold z/Z_SCALE (=*0.1) into W0 columns 0..7
        wf[t] = W0[t] * (k < 8 ? 0.1f : 1.0f);
    } else if (t < 96) {
        wf[t] = b0[t - 88];
    } else if (t < 160) {
        wf[t] = Wm[t - 96];
    } else if (t < 168) {
        wf[t] = bm[t - 160];
    } else if (t < 192) {
        wf[t] = Wo[t - 168];
    } else if (t < 195) {
        wf[t] = bo[t - 192];
    } else if (t < 195 + 24) {
        int j = t - 195;          // j = l*8 + f*2 + slot  (masks flat [3,4,2])
        // int64-masks hedge: valid int32 masks have every odd entry >= 1
        // (second element of a sorted distinct pair); int64-as-int32 has all
        // odd words == 0 (high words of values 0..7, little-endian).
        bool is64 = true;
        for (int q = 1; q < 24; q += 2) is64 = is64 && (masks[q] == 0);
        int c = is64 ? masks[2 * j] : masks[j];   // natural column index 0..7
        int l = j >> 3;
        int f = (j & 7) >> 1;                     // function id for this group
        wi[256 + l * 8 + c] = f;
    }
}

__global__ __launch_bounds__(256) void cppn_main(
    const float* __restrict__ xb,
    const float* __restrict__ yb,
    const float* __restrict__ rb,
    const float4* __restrict__ zb,         // 8 f32 per pixel = two float4
    const float* __restrict__ wf,          // ws floats (uniform -> s_load)
    const int* __restrict__ fid,           // funid base (ws ints + 256)
    float* __restrict__ out,
    int n) {
    int i = blockIdx.x * 256 + threadIdx.x;
    if (i >= n) return;

    float4 z0 = zb[2 * i];
    float4 z1 = zb[2 * i + 1];
    float in[11];
    in[0] = z0.x; in[1] = z0.y; in[2] = z0.z; in[3] = z0.w;
    in[4] = z1.x; in[5] = z1.y; in[6] = z1.z; in[7] = z1.w;
    in[8]  = xb[i];
    in[9]  = yb[i];
    in[10] = rb[i];

    float o[8];
#pragma unroll
    for (int h = 0; h < 8; ++h) {
        float acc = wf[88 + h];
#pragma unroll
        for (int k = 0; k < 11; ++k)
            acc = fmaf(wf[h * 11 + k], in[k], acc);
        o[h] = acc;
    }

#pragma unroll
    for (int l = 0; l < 3; ++l) {
        float p[8];
#pragma unroll
        for (int h = 0; h < 8; ++h) {
            float acc = wf[160 + h];
#pragma unroll
            for (int k = 0; k < 8; ++k)
                acc = fmaf(wf[96 + h * 8 + k], o[k], acc);
            p[h] = acc;
        }
#pragma unroll
        for (int h = 0; h < 8; ++h) {
            // wave-uniform activation id -> scalar branch, no divergence
            int f = __builtin_amdgcn_readfirstlane(fid[l * 8 + h]);
            float t = p[h];
            float v;
            if (f == 0) {
                v = __sinf(t);
            } else if (f == 1) {
                v = 0.3989422804014327f * __expf(-0.5f * t * t);
            } else if (f == 2) {
                // tanh(t) = 1 - 2/(e^{2t}+1); e=inf -> rcp(inf)=0 -> v=1 (safe)
                float e = __expf(2.0f * t);
                v = 1.0f - 2.0f * __builtin_amdgcn_rcpf(e + 1.0f);
            } else {
                v = t;   // identity
            }
            o[h] = 0.5f * (v + o[h]);
        }
    }

#pragma unroll
    for (int j = 0; j < 3; ++j) {
        float acc = wf[192 + j];
#pragma unroll
        for (int k = 0; k < 8; ++k)
            acc = fmaf(wf[168 + j * 8 + k], o[k], acc);
        float e = __expf(-acc);                       // sigmoid
        out[3 * i + j] = __builtin_amdgcn_rcpf(1.0f + e);
    }
}

extern "C" void kernel_launch(void* const* d_in, const int* in_sizes, int n_in,
                              void* d_out, int out_size, void* d_ws, size_t ws_size,
                              hipStream_t stream) {
    const float* xb = (const float*)d_in[0];
    const float* yb = (const float*)d_in[1];
    const float* rb = (const float*)d_in[2];
    const float* zb = (const float*)d_in[3];
    const float* W0 = (const float*)d_in[4];
    const float* b0 = (const float*)d_in[5];
    const float* Wm = (const float*)d_in[6];
    const float* bm = (const float*)d_in[7];
    const float* Wo = (const float*)d_in[8];
    const float* bo = (const float*)d_in[9];
    const int* masks = (const int*)d_in[10];

    float* wf = (float*)d_ws;
    int*   wi = (int*)d_ws;

    int n = in_sizes[0];   // N pixels

    cppn_prep<<<1, 256, 0, stream>>>(W0, b0, Wm, bm, Wo, bo, masks, wf, wi);
    cppn_main<<<(n + 255) / 256, 256, 0, stream>>>(
        xb, yb, rb, (const float4*)zb, wf, wi + 256,
        (float*)d_out, n);
}

// Round 3
// 258.839 us; speedup vs baseline: 1.0019x; 1.0019x over previous
//
#include <hip/hip_runtime.h>

// FC_CPPN: per-pixel tiny MLP, ALL float32 (inputs, weights, output).
//  d_in[0]=x[N], [1]=y[N], [2]=r[N], [3]=z[N,8], [4]=W0[8,11], [5]=b0[8],
//  [6]=Wm[8,8], [7]=bm[8], [8]=Wo[3,8], [9]=bo[3], [10]=masks[3,4,2] (int)
// out: float32 [N,3]
//
// Scaled-state formulation: u_l = 2^l * out_l.
//   pre_l   = (Wm*2^-l) u_l + bm          (prep stores 3 scaled Wm copies)
//   u_{l+1} = u_l + 2^l * act(pre_l)       (2^l = 1,2,4 -> inline consts)
//   result  = sigmoid((Wo/8) u_3 + bo)
//
// ws float layout:
//   [0,88)    W0 (cols 0..7 pre-scaled by 1/Z_SCALE=0.1)
//   [88,96)   b0
//   [96,288)  Wm*2^-l for l=0,1,2 (64 floats each)
//   [288,296) bm
//   [296,320) Wo/8
//   [320,323) bo
// ws int layout: [384,408) funid[l*8 + natural_column] = activation 0..3

__global__ void cppn_prep(const float* __restrict__ W0,
                          const float* __restrict__ b0,
                          const float* __restrict__ Wm,
                          const float* __restrict__ bm,
                          const float* __restrict__ Wo,
                          const float* __restrict__ bo,
                          const int* __restrict__ masks,
                          float* __restrict__ wf,
                          int* __restrict__ wi) {
    int t = threadIdx.x;
    if (t < 88) {
        int k = t % 11;
        wf[t] = W0[t] * (k < 8 ? 0.1f : 1.0f);      // fold z/Z_SCALE
    } else if (t < 96) {
        wf[t] = b0[t - 88];
    } else if (t < 288) {
        int j = t - 96;
        int l = j >> 6;                              // which scaled copy
        float s = (l == 0) ? 1.0f : (l == 1 ? 0.5f : 0.25f);
        wf[96 + j] = Wm[j & 63] * s;
    } else if (t < 296) {
        wf[t] = bm[t - 288];
    } else if (t < 320) {
        wf[t] = Wo[t - 296] * 0.125f;                // fold /8
    } else if (t < 323) {
        wf[t] = bo[t - 320];
    } else if (t < 323 + 24) {
        int j = t - 323;          // j = l*8 + f*2 + slot  (masks flat [3,4,2])
        // int64-masks hedge: valid int32 masks have every odd entry >= 1;
        // int64-as-int32 has all odd words == 0 (high words, little-endian).
        bool is64 = true;
        for (int q = 1; q < 24; q += 2) is64 = is64 && (masks[q] == 0);
        int c = is64 ? masks[2 * j] : masks[j];      // natural column 0..7
        int l = j >> 3;
        int f = (j & 7) >> 1;                        // activation id
        wi[384 + l * 8 + c] = f;
    }
}

#define PX 2   // pixels per thread

__global__ __launch_bounds__(256) void cppn_main(
    const float* __restrict__ xb,
    const float* __restrict__ yb,
    const float* __restrict__ rb,
    const float4* __restrict__ zb,         // 8 f32 per pixel = two float4
    const float* __restrict__ wf,          // ws floats (uniform -> s_load)
    const int* __restrict__ fid,           // funid base (ws ints + 384)
    float* __restrict__ out,
    int n) {
    int base = blockIdx.x * (256 * PX) + threadIdx.x;
    int idx[PX];
    bool ok[PX];
#pragma unroll
    for (int px = 0; px < PX; ++px) {
        idx[px] = base + px * 256;
        ok[px] = idx[px] < n;
    }

    float in[PX][11];
#pragma unroll
    for (int px = 0; px < PX; ++px) {
        int i = ok[px] ? idx[px] : 0;
        float4 z0 = zb[2 * i];
        float4 z1 = zb[2 * i + 1];
        in[px][0] = z0.x; in[px][1] = z0.y; in[px][2] = z0.z; in[px][3] = z0.w;
        in[px][4] = z1.x; in[px][5] = z1.y; in[px][6] = z1.z; in[px][7] = z1.w;
        in[px][8]  = xb[i];
        in[px][9]  = yb[i];
        in[px][10] = rb[i];
    }

    float u[PX][8];
#pragma unroll
    for (int h = 0; h < 8; ++h) {
#pragma unroll
        for (int px = 0; px < PX; ++px) {
            float acc = wf[88 + h];
#pragma unroll
            for (int k = 0; k < 11; ++k)
                acc = fmaf(wf[h * 11 + k], in[px][k], acc);
            u[px][h] = acc;
        }
    }

#pragma unroll
    for (int l = 0; l < 3; ++l) {
        const float* W = wf + 96 + 64 * l;            // Wm * 2^-l
        const float scale = (l == 0) ? 1.0f : (l == 1 ? 2.0f : 4.0f);
        float p[PX][8];
#pragma unroll
        for (int h = 0; h < 8; ++h) {
#pragma unroll
            for (int px = 0; px < PX; ++px) {
                float acc = wf[288 + h];
#pragma unroll
                for (int k = 0; k < 8; ++k)
                    acc = fmaf(W[h * 8 + k], u[px][k], acc);
                p[px][h] = acc;
            }
        }
#pragma unroll
        for (int h = 0; h < 8; ++h) {
            // wave-uniform activation id -> scalar branch, no divergence;
            // one branch serves PX pixels.
            int f = __builtin_amdgcn_readfirstlane(fid[l * 8 + h]);
            float v[PX];
            if (f == 0) {
#pragma unroll
                for (int px = 0; px < PX; ++px) v[px] = __sinf(p[px][h]);
            } else if (f == 1) {
#pragma unroll
                for (int px = 0; px < PX; ++px) {
                    float t = p[px][h];
                    v[px] = 0.3989422804014327f * __expf(-0.5f * t * t);
                }
            } else if (f == 2) {
#pragma unroll
                for (int px = 0; px < PX; ++px) {
                    // tanh(t) = 1 - 2/(e^{2t}+1); e=inf -> rcp=0 -> v=1 (safe)
                    float e = __expf(2.0f * p[px][h]);
                    v[px] = fmaf(-2.0f, __builtin_amdgcn_rcpf(e + 1.0f), 1.0f);
                }
            } else {
#pragma unroll
                for (int px = 0; px < PX; ++px) v[px] = p[px][h];
            }
#pragma unroll
            for (int px = 0; px < PX; ++px)
                u[px][h] = fmaf(scale, v[px], u[px][h]);   // inline-const scale
        }
    }

#pragma unroll
    for (int j = 0; j < 3; ++j) {
#pragma unroll
        for (int px = 0; px < PX; ++px) {
            float acc = wf[320 + j];
#pragma unroll
            for (int k = 0; k < 8; ++k)
                acc = fmaf(wf[296 + j * 8 + k], u[px][k], acc);
            float e = __expf(-acc);                        // sigmoid
            float v = __builtin_amdgcn_rcpf(1.0f + e);
            if (ok[px]) out[3 * idx[px] + j] = v;
        }
    }
}

extern "C" void kernel_launch(void* const* d_in, const int* in_sizes, int n_in,
                              void* d_out, int out_size, void* d_ws, size_t ws_size,
                              hipStream_t stream) {
    const float* xb = (const float*)d_in[0];
    const float* yb = (const float*)d_in[1];
    const float* rb = (const float*)d_in[2];
    const float* zb = (const float*)d_in[3];
    const float* W0 = (const float*)d_in[4];
    const float* b0 = (const float*)d_in[5];
    const float* Wm = (const float*)d_in[6];
    const float* bm = (const float*)d_in[7];
    const float* Wo = (const float*)d_in[8];
    const float* bo = (const float*)d_in[9];
    const int* masks = (const int*)d_in[10];

    float* wf = (float*)d_ws;
    int*   wi = (int*)d_ws;

    int n = in_sizes[0];   // N pixels

    cppn_prep<<<1, 512, 0, stream>>>(W0, b0, Wm, bm, Wo, bo, masks, wf, wi);
    int per_block = 256 * PX;
    cppn_main<<<(n + per_block - 1) / per_block, 256, 0, stream>>>(
        xb, yb, rb, (const float4*)zb, wf, wi + 384,
        (float*)d_out, n);
}